// Round 11
// baseline (565.295 us; speedup 1.0000x reference)
//
#include <hip/hip_runtime.h>
#include <hip/hip_bf16.h>
#include <math.h>

#define NCLS 20
#define KDIM 128
#define ALPHA 0.7f
#define BETA 1.5f

// ws float layout:
// [0,2560) sums | 2560 cnt | 2580 intra | 2600 hist(int) | 2620 cur(int)
// | 2640 barrier counters(int,4) | pairs (u64) at float-index 4096
#define WS_SUMS 0
#define WS_CNT 2560
#define WS_INTRA 2580
#define WS_HIST 2600
#define WS_CUR 2620
#define WS_BAR 2640
#define WS_ZERO_N 2656
#define WS_PAIRS 4096
#define WS_NEEDED ((size_t)(WS_PAIRS + 2 * 262144) * 4)

#define NB 1024
#define BLK 256

#define ALD(p) __hip_atomic_load((p), __ATOMIC_RELAXED, __HIP_MEMORY_SCOPE_AGENT)
#define AST(p, v) __hip_atomic_store((p), (v), __ATOMIC_RELAXED, __HIP_MEMORY_SCOPE_AGENT)

__global__ void k_init(float* ws) {
    const int i = blockIdx.x * BLK + threadIdx.x;
    if (i < WS_ZERO_N) ws[i] = 0.0f;
}

__device__ inline void gridbar(int* bar, int nb) {
    __syncthreads();
    if (threadIdx.x == 0) {
        __threadfence();
        __hip_atomic_fetch_add(bar, 1, __ATOMIC_ACQ_REL, __HIP_MEMORY_SCOPE_AGENT);
        while (__hip_atomic_load(bar, __ATOMIC_ACQUIRE, __HIP_MEMORY_SCOPE_AGENT) < nb) {
            __builtin_amdgcn_s_sleep(1);
        }
        __threadfence();
    }
    __syncthreads();
}

// ---- fused persistent kernel: hist -> scatter(sort) -> gather-sum -> intra -> final ----
__global__ void __launch_bounds__(BLK, 4) k_main(const float* __restrict__ pts,
                                                 const int* __restrict__ t,
                                                 const float4* __restrict__ emb4,
                                                 float* __restrict__ ws,
                                                 float* __restrict__ out, int N) {
    __shared__ float smem[2816];
    const int tid = threadIdx.x;
    int* bar = (int*)&ws[WS_BAR];
    int* ih = (int*)&smem[2580];

    // ---- P1: histogram (one point per thread; N == NB*BLK guaranteed by host) ----
    if (tid < NCLS) ih[tid] = 0;
    __syncthreads();
    const int myg = blockIdx.x * BLK + tid;
    int myc = -1;
    if (myg < N) {
        myc = t[myg];
        atomicAdd(&ih[myc], 1);
    }
    __syncthreads();
    if (tid < NCLS && ih[tid]) atomicAdd((int*)&ws[WS_HIST] + tid, ih[tid]);
    gridbar(bar + 0, NB);

    // ---- P2: scatter (class,idx) pairs into class-sorted order ----
    {
        int* gb = (int*)&smem[2600];
        int* lcur = (int*)&smem[2620];
        const int* gh = (const int*)&ws[WS_HIST];
        if (tid < NCLS) {
            int basec = 0, own = 0;
            for (int i = 0; i < NCLS; i++) {
                const int hv = ALD(&gh[i]);
                if (i < tid) basec += hv;
                if (i == tid) own = hv;
            }
            gb[tid] = basec + atomicAdd((int*)&ws[WS_CUR] + tid, ih[tid]);
            lcur[tid] = 0;
            if (blockIdx.x == 0) AST(&ws[WS_CNT + tid], (float)own);
        }
        __syncthreads();
        if (myc >= 0) {
            const int r = atomicAdd(&lcur[myc], 1);
            const unsigned long long pv =
                (unsigned long long)(unsigned)myc |
                ((unsigned long long)(unsigned)myg << 32);
            AST((unsigned long long*)&ws[WS_PAIRS] + (gb[myc] + r), pv);
        }
    }
    gridbar(bar + 1, NB);

    // ---- P3: sorted gather segment-sum (R8 structure, half-wave class fixed) ----
    {
        float* lsum = smem;
        for (int i = tid; i < NCLS * KDIM; i += BLK) lsum[i] = 0.0f;
        __syncthreads();
        const int s = tid & 31;
        const int base = (blockIdx.x * 8 + (tid >> 5)) * 32;
        const unsigned long long* pu = (const unsigned long long*)&ws[WS_PAIRS];
        unsigned long long pv = ALD(&pu[base]);
        int ccur = (int)(unsigned)(pv & 0xffffffffu);
        float4 acc = emb4[(size_t)(unsigned)(pv >> 32) * 32 + s];
        for (int j = 1; j < 32; j++) {
            pv = ALD(&pu[base + j]);
            const int c = (int)(unsigned)(pv & 0xffffffffu);
            const float4 v = emb4[(size_t)(unsigned)(pv >> 32) * 32 + s];
            if (c != ccur) {
                float* a = &lsum[ccur * KDIM + 4 * s];
                unsafeAtomicAdd(a + 0, acc.x);
                unsafeAtomicAdd(a + 1, acc.y);
                unsafeAtomicAdd(a + 2, acc.z);
                unsafeAtomicAdd(a + 3, acc.w);
                ccur = c;
                acc = v;
            } else {
                acc.x += v.x; acc.y += v.y; acc.z += v.z; acc.w += v.w;
            }
        }
        float* a = &lsum[ccur * KDIM + 4 * s];
        unsafeAtomicAdd(a + 0, acc.x);
        unsafeAtomicAdd(a + 1, acc.y);
        unsafeAtomicAdd(a + 2, acc.z);
        unsafeAtomicAdd(a + 3, acc.w);
        __syncthreads();
        for (int i = tid; i < NCLS * KDIM; i += BLK)
            if (lsum[i] != 0.0f) unsafeAtomicAdd(&ws[WS_SUMS + i], lsum[i]);
    }
    gridbar(bar + 2, NB);

    // ---- P4: intra (emb L3-hot from P3) ----
    {
        float* lmean = smem;
        float* lintra = &smem[2560];
        for (int i = tid; i < NCLS * KDIM; i += BLK) {
            const float sv = ALD(&ws[WS_SUMS + i]);
            const float cv = ALD(&ws[WS_CNT + i / KDIM]);
            lmean[i] = sv / fmaxf(cv, 1.0f);
        }
        if (tid < NCLS) lintra[tid] = 0.0f;
        __syncthreads();
        const int s = tid & 31;
        const int pp = tid >> 5;
        const int stride = NB * 8;
        for (int p = blockIdx.x * 8 + pp; p < N; p += 2 * stride) {
            const int p1 = p + stride;
            {
                const int c = t[p];
                const float4 v = emb4[(size_t)p * 32 + s];
                const float4 m = *(const float4*)&lmean[c * KDIM + 4 * s];
                float dx = v.x - m.x, dy = v.y - m.y, dz = v.z - m.z, dw = v.w - m.w;
                float d2 = dx * dx + dy * dy + dz * dz + dw * dw;
                for (int off = 16; off >= 1; off >>= 1) d2 += __shfl_down(d2, off, 32);
                if (s == 0) {
                    const float d = sqrtf(d2);
                    const float px = pts[(size_t)p * 3 + 0];
                    const float py = pts[(size_t)p * 3 + 1];
                    const float pz = pts[(size_t)p * 3 + 2];
                    const float r = sqrtf(px * px + py * py + pz * pz);
                    const float g = 1.0f / (1.0f + expf(-r));
                    const float h = fmaxf(d - ALPHA, 0.0f);
                    unsafeAtomicAdd(&lintra[c], g * h * h);
                }
            }
            if (p1 < N) {
                const int c = t[p1];
                const float4 v = emb4[(size_t)p1 * 32 + s];
                const float4 m = *(const float4*)&lmean[c * KDIM + 4 * s];
                float dx = v.x - m.x, dy = v.y - m.y, dz = v.z - m.z, dw = v.w - m.w;
                float d2 = dx * dx + dy * dy + dz * dz + dw * dw;
                for (int off = 16; off >= 1; off >>= 1) d2 += __shfl_down(d2, off, 32);
                if (s == 0) {
                    const float d = sqrtf(d2);
                    const float px = pts[(size_t)p1 * 3 + 0];
                    const float py = pts[(size_t)p1 * 3 + 1];
                    const float pz = pts[(size_t)p1 * 3 + 2];
                    const float r = sqrtf(px * px + py * py + pz * pz);
                    const float g = 1.0f / (1.0f + expf(-r));
                    const float h = fmaxf(d - ALPHA, 0.0f);
                    unsafeAtomicAdd(&lintra[c], g * h * h);
                }
            }
        }
        __syncthreads();
        if (tid < NCLS) unsafeAtomicAdd(&ws[WS_INTRA + tid], lintra[tid]);
    }
    gridbar(bar + 3, NB);

    // ---- P5: final (block 0; lmean still live in its LDS) ----
    if (blockIdx.x != 0) return;
    {
        float* lmean = smem;
        float* red = &smem[2560];
        float acc = 0.0f;
        for (int idx = tid; idx < 361; idx += BLK) {
            const int i = idx / 19 + 1;
            const int j = idx % 19 + 1;
            if (i != j) {
                float sq = 0.0f;
                const float* mi = lmean + i * KDIM;
                const float* mj = lmean + j * KDIM;
                for (int k = 0; k < KDIM; k++) {
                    const float df = mi[k] - mj[k];
                    sq += df * df;
                }
                const float dist = sqrtf(sq);
                const float h = fmaxf(BETA - dist, 0.0f);
                acc += h * h;
            }
        }
        red[tid] = acc;
        __syncthreads();
        for (int st = 128; st >= 1; st >>= 1) {
            if (tid < st) red[tid] += red[tid + st];
            __syncthreads();
        }
        if (tid == 0) {
            float intra = 0.0f;
            for (int c = 1; c < NCLS; c++) {
                const float iv = ALD(&ws[WS_INTRA + c]);
                const float cv = ALD(&ws[WS_CNT + c]);
                intra += iv / fmaxf(cv, 1.0f);
            }
            out[0] = intra / (float)NCLS + red[0] / (float)(NCLS * (NCLS - 1));
        }
    }
}

// =================== fallback path (R6-proven, no co-residency needed) ===================
#define FB_BLK 128
#define FB_GRID 2048
__global__ void __launch_bounds__(FB_BLK) k_sums_fb(const float4* __restrict__ emb4,
                                                    const int* __restrict__ t,
                                                    float* ws, int N) {
    __shared__ float lsum[2][NCLS * KDIM];
    __shared__ float lcnt[NCLS];
    __shared__ int lds_t[FB_BLK];
    const int tid = threadIdx.x;
    const int w = tid >> 6, k = tid & 63;
    const int half = k >> 5;
    const int k31 = k & 31;
    for (int i = tid; i < 2 * NCLS * KDIM; i += FB_BLK) (&lsum[0][0])[i] = 0.0f;
    if (tid < NCLS) lcnt[tid] = 0.0f;
    __syncthreads();
    const int chunk = blockIdx.x * FB_BLK;
    const int npts = min(FB_BLK, N - chunk);
    if (tid < npts) {
        const int c = t[chunk + tid];
        lds_t[tid] = c;
        unsafeAtomicAdd(&lcnt[c], 1.0f);
    }
    __syncthreads();
    float* L = lsum[w];
    for (int q = 32 * w; q < 32 * w + 32; q++) {
        const int pl = 2 * q + half;
        if (pl < npts) {
            const int c = lds_t[pl];
            const float4 v = emb4[(size_t)(chunk + pl) * 32 + k31];
            const int cA = __shfl(c, 0, 64);
            const int cB = __shfl(c, 32, 64);
            if (cA == cB) {
                float4 vv;
                vv.x = v.x + __shfl_xor(v.x, 32, 64);
                vv.y = v.y + __shfl_xor(v.y, 32, 64);
                vv.z = v.z + __shfl_xor(v.z, 32, 64);
                vv.w = v.w + __shfl_xor(v.w, 32, 64);
                if (half == 0) {
                    float4* a = (float4*)&L[cA * KDIM + 4 * k31];
                    float4 o = *a;
                    o.x += vv.x; o.y += vv.y; o.z += vv.z; o.w += vv.w;
                    *a = o;
                }
            } else {
                float4* a = (float4*)&L[c * KDIM + 4 * k31];
                float4 o = *a;
                o.x += v.x; o.y += v.y; o.z += v.z; o.w += v.w;
                *a = o;
            }
        }
    }
    __syncthreads();
    for (int i = tid; i < NCLS * KDIM; i += FB_BLK)
        unsafeAtomicAdd(&ws[WS_SUMS + i], lsum[0][i] + lsum[1][i]);
    if (tid < NCLS) unsafeAtomicAdd(&ws[WS_CNT + tid], lcnt[tid]);
}

__global__ void __launch_bounds__(256) k_intra_fb(const float4* __restrict__ emb4,
                                                  const int* __restrict__ t,
                                                  const float* __restrict__ pts,
                                                  float* ws, int N) {
    __shared__ float lmean[NCLS * KDIM];
    __shared__ float lintra[NCLS];
    const int tid = threadIdx.x;
    for (int i = tid; i < NCLS * KDIM; i += 256) {
        const float cnt = ws[WS_CNT + i / KDIM];
        lmean[i] = ws[WS_SUMS + i] / fmaxf(cnt, 1.0f);
    }
    if (tid < NCLS) lintra[tid] = 0.0f;
    __syncthreads();
    const int s = tid & 31;
    const int pp = tid >> 5;
    const int stride = FB_GRID * 8;
    for (int p = blockIdx.x * 8 + pp; p < N; p += stride) {
        const int c = t[p];
        const float4 v = emb4[(size_t)p * 32 + s];
        const float4 m = *(const float4*)&lmean[c * KDIM + 4 * s];
        float dx = v.x - m.x, dy = v.y - m.y, dz = v.z - m.z, dw = v.w - m.w;
        float d2 = dx * dx + dy * dy + dz * dz + dw * dw;
        for (int off = 16; off >= 1; off >>= 1) d2 += __shfl_down(d2, off, 32);
        if (s == 0) {
            const float d = sqrtf(d2);
            const float px = pts[(size_t)p * 3 + 0];
            const float py = pts[(size_t)p * 3 + 1];
            const float pz = pts[(size_t)p * 3 + 2];
            const float r = sqrtf(px * px + py * py + pz * pz);
            const float g = 1.0f / (1.0f + expf(-r));
            const float h = fmaxf(d - ALPHA, 0.0f);
            unsafeAtomicAdd(&lintra[c], g * h * h);
        }
    }
    __syncthreads();
    if (tid < NCLS) unsafeAtomicAdd(&ws[WS_INTRA + tid], lintra[tid]);
}

__global__ void __launch_bounds__(256) k_final_fb(const float* ws, float* out) {
    __shared__ float lmean[NCLS * KDIM];
    __shared__ float red[256];
    const int tid = threadIdx.x;
    for (int i = tid; i < NCLS * KDIM; i += 256) {
        const float cnt = ws[WS_CNT + i / KDIM];
        lmean[i] = ws[WS_SUMS + i] / fmaxf(cnt, 1.0f);
    }
    __syncthreads();
    float acc = 0.0f;
    for (int idx = tid; idx < 361; idx += 256) {
        const int i = idx / 19 + 1;
        const int j = idx % 19 + 1;
        if (i != j) {
            float sq = 0.0f;
            const float* mi = lmean + i * KDIM;
            const float* mj = lmean + j * KDIM;
            for (int k = 0; k < KDIM; k++) {
                const float df = mi[k] - mj[k];
                sq += df * df;
            }
            const float dist = sqrtf(sq);
            const float h = fmaxf(BETA - dist, 0.0f);
            acc += h * h;
        }
    }
    red[tid] = acc;
    __syncthreads();
    for (int st = 128; st >= 1; st >>= 1) {
        if (tid < st) red[tid] += red[tid + st];
        __syncthreads();
    }
    if (tid == 0) {
        float intra = 0.0f;
        for (int c = 1; c < NCLS; c++)
            intra += ws[WS_INTRA + c] / fmaxf(ws[WS_CNT + c], 1.0f);
        out[0] = intra / (float)NCLS + red[0] / (float)(NCLS * (NCLS - 1));
    }
}

extern "C" void kernel_launch(void* const* d_in, const int* in_sizes, int n_in,
                              void* d_out, int out_size, void* d_ws, size_t ws_size,
                              hipStream_t stream) {
    const float* pts = (const float*)d_in[0];
    const int* t = (const int*)d_in[1];
    const float4* emb4 = (const float4*)d_in[2];
    float* out = (float*)d_out;
    float* ws = (float*)d_ws;
    const int N = in_sizes[1];

    int maxb = 0;
    const hipError_t qe =
        hipOccupancyMaxActiveBlocksPerMultiprocessor(&maxb, k_main, BLK, 0);
    const bool coop = (qe == hipSuccess) && (maxb >= 4) &&
                      (ws_size >= WS_NEEDED) && (N == NB * BLK);

    k_init<<<(WS_ZERO_N + BLK - 1) / BLK, BLK, 0, stream>>>(ws);
    if (coop) {
        k_main<<<NB, BLK, 0, stream>>>(pts, t, emb4, ws, out, N);
    } else {
        k_sums_fb<<<FB_GRID, FB_BLK, 0, stream>>>(emb4, t, ws, N);
        k_intra_fb<<<FB_GRID, 256, 0, stream>>>(emb4, t, pts, ws, N);
        k_final_fb<<<1, 256, 0, stream>>>(ws, out);
    }
}

// Round 12
// 110.759 us; speedup vs baseline: 5.1038x; 5.1038x over previous
//
#include <hip/hip_runtime.h>
#include <hip/hip_bf16.h>
#include <math.h>

#define NCLS 20
#define KDIM 128
#define ALPHA 0.7f
#define BETA 1.5f

// ws float layout:
// [0,2560) class sums | [2560,+20) intra partials | [2580,+20) gcur(int)
// | buckets(int) at float-index 4096: class c -> [WS_BKT + c*N, +cnt_c)
#define WS_SUMS 0
#define WS_INTRA 2560
#define WS_CUR 2580
#define WS_ZERO_N 2600
#define WS_BKT 4096

#define GRID 2048
#define SUMS_GRID 1027   // covers worst-case sum(ceil(cnt_c/32)) = 8192+19 half-waves

__global__ void k_init(float* ws) {
    const int tid = threadIdx.x;
    for (int i = tid; i < WS_ZERO_N; i += 256) ws[i] = 0.0f;
}

// ---- S1: scatter point indices into class-strided buckets (no hist/scan) ----
__global__ void __launch_bounds__(256) k_scatter(const int* __restrict__ t,
                                                 float* __restrict__ ws, int N) {
    __shared__ int ih[NCLS], lbase[NCLS];
    const int tid = threadIdx.x;
    if (tid < NCLS) ih[tid] = 0;
    __syncthreads();
    const int g = blockIdx.x * 256 + tid;
    int c = -1, r = 0;
    if (g < N) {
        c = t[g];
        r = atomicAdd(&ih[c], 1);          // native ds_add_rtn_u32: local rank
    }
    __syncthreads();
    if (tid < NCLS && ih[tid]) lbase[tid] = atomicAdd((int*)&ws[WS_CUR] + tid, ih[tid]);
    __syncthreads();
    if (c >= 0) {
        int* bkt = (int*)&ws[WS_BKT];
        bkt[(size_t)c * N + lbase[c] + r] = g;
    }
}

// ---- pass 1: sorted gather segment-sum; each half-wave = 32 entries of ONE
// class. Lane-coalesced index load + shfl broadcast + 8-deep batched 512B
// gathers + register accumulate; ONE LDS-atomic flush per half-wave (proven
// R7 flush structure), then one block-level global flush. ----
__global__ void __launch_bounds__(256) k_sums(const float4* __restrict__ emb4,
                                              float* __restrict__ ws, int N) {
    __shared__ float lsum[NCLS * KDIM];
    const int tid = threadIdx.x;
    for (int i = tid; i < NCLS * KDIM; i += 256) lsum[i] = 0.0f;
    __syncthreads();

    const int s = tid & 31;
    const int u = blockIdx.x * 8 + (tid >> 5);   // virtual half-wave id
    const int* gc = (const int*)&ws[WS_CUR];

    // map u -> (class, offset, m) via padded prefix over the 20 counts
    int cls = -1, off = 0, m = 0;
    {
        int cum = 0;
#pragma unroll
        for (int c = 0; c < NCLS; c++) {
            const int cnt = gc[c];
            const int v = (cnt + 31) >> 5;
            if (u >= cum && u < cum + v) {
                cls = c;
                off = (u - cum) * 32;
                m = min(32, cnt - off);
            }
            cum += v;
        }
    }

    if (cls >= 0) {
        const int* bkt = (const int*)&ws[WS_BKT] + (size_t)cls * N + off;
        const int bidx = bkt[min(s, m - 1)];     // coalesced 128B per half-wave
        float4 acc = make_float4(0.f, 0.f, 0.f, 0.f);
        if (m == 32) {
#pragma unroll
            for (int j0 = 0; j0 < 32; j0 += 8) {
                float4 v0, v1, v2, v3, v4, v5, v6, v7;
#define G(jj) { const int idx = __shfl(bidx, j0 + jj, 32);  \
                v##jj = emb4[(size_t)idx * 32 + s]; }
                G(0) G(1) G(2) G(3) G(4) G(5) G(6) G(7)
#undef G
                acc.x += v0.x + v1.x + v2.x + v3.x + v4.x + v5.x + v6.x + v7.x;
                acc.y += v0.y + v1.y + v2.y + v3.y + v4.y + v5.y + v6.y + v7.y;
                acc.z += v0.z + v1.z + v2.z + v3.z + v4.z + v5.z + v6.z + v7.z;
                acc.w += v0.w + v1.w + v2.w + v3.w + v4.w + v5.w + v6.w + v7.w;
            }
        } else {
            for (int j = 0; j < m; j++) {
                const int idx = __shfl(bidx, j, 32);
                const float4 v = emb4[(size_t)idx * 32 + s];
                acc.x += v.x; acc.y += v.y; acc.z += v.z; acc.w += v.w;
            }
        }
        float* a = &lsum[cls * KDIM + 4 * s];
        unsafeAtomicAdd(a + 0, acc.x);
        unsafeAtomicAdd(a + 1, acc.y);
        unsafeAtomicAdd(a + 2, acc.z);
        unsafeAtomicAdd(a + 3, acc.w);
    }
    __syncthreads();

    for (int i = tid; i < NCLS * KDIM; i += 256)
        if (lsum[i] != 0.0f) unsafeAtomicAdd(&ws[WS_SUMS + i], lsum[i]);
}

// ---- pass 2 (proven; counts read from int cursors) ----
__global__ void __launch_bounds__(256) k_intra(const float4* __restrict__ emb4,
                                               const int* __restrict__ t,
                                               const float* __restrict__ pts,
                                               float* __restrict__ ws, int N) {
    __shared__ float lmean[NCLS * KDIM];
    __shared__ float lintra[NCLS];
    const int tid = threadIdx.x;
    const int* gc = (const int*)&ws[WS_CUR];
    for (int i = tid; i < NCLS * KDIM; i += 256) {
        const float cnt = (float)gc[i / KDIM];
        lmean[i] = ws[WS_SUMS + i] / fmaxf(cnt, 1.0f);
    }
    if (tid < NCLS) lintra[tid] = 0.0f;
    __syncthreads();

    const int s = tid & 31;
    const int pp = tid >> 5;
    const int stride = GRID * 8;
    for (int p = blockIdx.x * 8 + pp; p < N; p += 2 * stride) {
        const int p1 = p + stride;
        {
            const int c = t[p];
            const float4 v = emb4[(size_t)p * 32 + s];
            const float4 mm = *(const float4*)&lmean[c * KDIM + 4 * s];
            float dx = v.x - mm.x, dy = v.y - mm.y, dz = v.z - mm.z, dw = v.w - mm.w;
            float d2 = dx * dx + dy * dy + dz * dz + dw * dw;
            for (int off = 16; off >= 1; off >>= 1) d2 += __shfl_down(d2, off, 32);
            if (s == 0) {
                const float d = sqrtf(d2);
                const float px = pts[(size_t)p * 3 + 0];
                const float py = pts[(size_t)p * 3 + 1];
                const float pz = pts[(size_t)p * 3 + 2];
                const float r = sqrtf(px * px + py * py + pz * pz);
                const float g = 1.0f / (1.0f + expf(-r));
                const float h = fmaxf(d - ALPHA, 0.0f);
                unsafeAtomicAdd(&lintra[c], g * h * h);
            }
        }
        if (p1 < N) {
            const int c = t[p1];
            const float4 v = emb4[(size_t)p1 * 32 + s];
            const float4 mm = *(const float4*)&lmean[c * KDIM + 4 * s];
            float dx = v.x - mm.x, dy = v.y - mm.y, dz = v.z - mm.z, dw = v.w - mm.w;
            float d2 = dx * dx + dy * dy + dz * dz + dw * dw;
            for (int off = 16; off >= 1; off >>= 1) d2 += __shfl_down(d2, off, 32);
            if (s == 0) {
                const float d = sqrtf(d2);
                const float px = pts[(size_t)p1 * 3 + 0];
                const float py = pts[(size_t)p1 * 3 + 1];
                const float pz = pts[(size_t)p1 * 3 + 2];
                const float r = sqrtf(px * px + py * py + pz * pz);
                const float g = 1.0f / (1.0f + expf(-r));
                const float h = fmaxf(d - ALPHA, 0.0f);
                unsafeAtomicAdd(&lintra[c], g * h * h);
            }
        }
    }
    __syncthreads();
    if (tid < NCLS) unsafeAtomicAdd(&ws[WS_INTRA + tid], lintra[tid]);
}

// ---- final ----
__global__ void __launch_bounds__(256) k_final(const float* __restrict__ ws,
                                               float* __restrict__ out) {
    __shared__ float lmean[NCLS * KDIM];
    __shared__ float red[256];
    const int tid = threadIdx.x;
    const int* gc = (const int*)&ws[WS_CUR];
    for (int i = tid; i < NCLS * KDIM; i += 256) {
        const float cnt = (float)gc[i / KDIM];
        lmean[i] = ws[WS_SUMS + i] / fmaxf(cnt, 1.0f);
    }
    __syncthreads();

    float acc = 0.0f;
    for (int idx = tid; idx < 361; idx += 256) {
        const int i = idx / 19 + 1;
        const int j = idx % 19 + 1;
        if (i != j) {
            float sq = 0.0f;
            const float* mi = lmean + i * KDIM;
            const float* mj = lmean + j * KDIM;
            for (int k = 0; k < KDIM; k++) {
                const float df = mi[k] - mj[k];
                sq += df * df;
            }
            const float dist = sqrtf(sq);
            const float h = fmaxf(BETA - dist, 0.0f);
            acc += h * h;
        }
    }
    red[tid] = acc;
    __syncthreads();
    for (int st = 128; st >= 1; st >>= 1) {
        if (tid < st) red[tid] += red[tid + st];
        __syncthreads();
    }
    if (tid == 0) {
        float intra = 0.0f;
        for (int c = 1; c < NCLS; c++)
            intra += ws[WS_INTRA + c] / fmaxf((float)gc[c], 1.0f);
        out[0] = intra / (float)NCLS + red[0] / (float)(NCLS * (NCLS - 1));
    }
}

// =================== fallback (R6-proven; used only if ws too small) ===================
#define FB_BLK 128
#define FB_GRID 2048
#define FBW_SUMS 0
#define FBW_CNT 2560
#define FBW_INTRA 2580
__global__ void __launch_bounds__(256) k_init_fb(float* ws) {
    const int tid = threadIdx.x;
    for (int i = tid; i < 2600; i += 256) ws[i] = 0.0f;
}
__global__ void __launch_bounds__(FB_BLK) k_sums_fb(const float4* __restrict__ emb4,
                                                    const int* __restrict__ t,
                                                    float* ws, int N) {
    __shared__ float lsum[2][NCLS * KDIM];
    __shared__ float lcnt[NCLS];
    __shared__ int lds_t[FB_BLK];
    const int tid = threadIdx.x;
    const int w = tid >> 6, k = tid & 63;
    const int half = k >> 5;
    const int k31 = k & 31;
    for (int i = tid; i < 2 * NCLS * KDIM; i += FB_BLK) (&lsum[0][0])[i] = 0.0f;
    if (tid < NCLS) lcnt[tid] = 0.0f;
    __syncthreads();
    const int chunk = blockIdx.x * FB_BLK;
    const int npts = min(FB_BLK, N - chunk);
    if (tid < npts) {
        const int c = t[chunk + tid];
        lds_t[tid] = c;
        unsafeAtomicAdd(&lcnt[c], 1.0f);
    }
    __syncthreads();
    float* L = lsum[w];
    for (int q = 32 * w; q < 32 * w + 32; q++) {
        const int pl = 2 * q + half;
        if (pl < npts) {
            const int c = lds_t[pl];
            const float4 v = emb4[(size_t)(chunk + pl) * 32 + k31];
            const int cA = __shfl(c, 0, 64);
            const int cB = __shfl(c, 32, 64);
            if (cA == cB) {
                float4 vv;
                vv.x = v.x + __shfl_xor(v.x, 32, 64);
                vv.y = v.y + __shfl_xor(v.y, 32, 64);
                vv.z = v.z + __shfl_xor(v.z, 32, 64);
                vv.w = v.w + __shfl_xor(v.w, 32, 64);
                if (half == 0) {
                    float4* a = (float4*)&L[cA * KDIM + 4 * k31];
                    float4 o = *a;
                    o.x += vv.x; o.y += vv.y; o.z += vv.z; o.w += vv.w;
                    *a = o;
                }
            } else {
                float4* a = (float4*)&L[c * KDIM + 4 * k31];
                float4 o = *a;
                o.x += v.x; o.y += v.y; o.z += v.z; o.w += v.w;
                *a = o;
            }
        }
    }
    __syncthreads();
    for (int i = tid; i < NCLS * KDIM; i += FB_BLK)
        unsafeAtomicAdd(&ws[FBW_SUMS + i], lsum[0][i] + lsum[1][i]);
    if (tid < NCLS) unsafeAtomicAdd(&ws[FBW_CNT + tid], lcnt[tid]);
}
__global__ void __launch_bounds__(256) k_intra_fb(const float4* __restrict__ emb4,
                                                  const int* __restrict__ t,
                                                  const float* __restrict__ pts,
                                                  float* ws, int N) {
    __shared__ float lmean[NCLS * KDIM];
    __shared__ float lintra[NCLS];
    const int tid = threadIdx.x;
    for (int i = tid; i < NCLS * KDIM; i += 256)
        lmean[i] = ws[FBW_SUMS + i] / fmaxf(ws[FBW_CNT + i / KDIM], 1.0f);
    if (tid < NCLS) lintra[tid] = 0.0f;
    __syncthreads();
    const int s = tid & 31;
    const int pp = tid >> 5;
    const int stride = FB_GRID * 8;
    for (int p = blockIdx.x * 8 + pp; p < N; p += stride) {
        const int c = t[p];
        const float4 v = emb4[(size_t)p * 32 + s];
        const float4 mm = *(const float4*)&lmean[c * KDIM + 4 * s];
        float dx = v.x - mm.x, dy = v.y - mm.y, dz = v.z - mm.z, dw = v.w - mm.w;
        float d2 = dx * dx + dy * dy + dz * dz + dw * dw;
        for (int off = 16; off >= 1; off >>= 1) d2 += __shfl_down(d2, off, 32);
        if (s == 0) {
            const float d = sqrtf(d2);
            const float px = pts[(size_t)p * 3 + 0];
            const float py = pts[(size_t)p * 3 + 1];
            const float pz = pts[(size_t)p * 3 + 2];
            const float r = sqrtf(px * px + py * py + pz * pz);
            const float g = 1.0f / (1.0f + expf(-r));
            const float h = fmaxf(d - ALPHA, 0.0f);
            unsafeAtomicAdd(&lintra[c], g * h * h);
        }
    }
    __syncthreads();
    if (tid < NCLS) unsafeAtomicAdd(&ws[FBW_INTRA + tid], lintra[tid]);
}
__global__ void __launch_bounds__(256) k_final_fb(const float* ws, float* out) {
    __shared__ float lmean[NCLS * KDIM];
    __shared__ float red[256];
    const int tid = threadIdx.x;
    for (int i = tid; i < NCLS * KDIM; i += 256)
        lmean[i] = ws[FBW_SUMS + i] / fmaxf(ws[FBW_CNT + i / KDIM], 1.0f);
    __syncthreads();
    float acc = 0.0f;
    for (int idx = tid; idx < 361; idx += 256) {
        const int i = idx / 19 + 1;
        const int j = idx % 19 + 1;
        if (i != j) {
            float sq = 0.0f;
            const float* mi = lmean + i * KDIM;
            const float* mj = lmean + j * KDIM;
            for (int k = 0; k < KDIM; k++) {
                const float df = mi[k] - mj[k];
                sq += df * df;
            }
            const float dist = sqrtf(sq);
            const float h = fmaxf(BETA - dist, 0.0f);
            acc += h * h;
        }
    }
    red[tid] = acc;
    __syncthreads();
    for (int st = 128; st >= 1; st >>= 1) {
        if (tid < st) red[tid] += red[tid + st];
        __syncthreads();
    }
    if (tid == 0) {
        float intra = 0.0f;
        for (int c = 1; c < NCLS; c++)
            intra += ws[FBW_INTRA + c] / fmaxf(ws[FBW_CNT + c], 1.0f);
        out[0] = intra / (float)NCLS + red[0] / (float)(NCLS * (NCLS - 1));
    }
}

extern "C" void kernel_launch(void* const* d_in, const int* in_sizes, int n_in,
                              void* d_out, int out_size, void* d_ws, size_t ws_size,
                              hipStream_t stream) {
    const float* pts = (const float*)d_in[0];
    const int* t = (const int*)d_in[1];
    const float4* emb4 = (const float4*)d_in[2];
    float* out = (float*)d_out;
    float* ws = (float*)d_ws;
    const int N = in_sizes[1];
    const size_t need = ((size_t)WS_BKT + (size_t)NCLS * (size_t)N) * 4;

    if (ws_size >= need) {
        k_init<<<1, 256, 0, stream>>>(ws);
        k_scatter<<<(N + 255) / 256, 256, 0, stream>>>(t, ws, N);
        k_sums<<<SUMS_GRID, 256, 0, stream>>>(emb4, ws, N);
        k_intra<<<GRID, 256, 0, stream>>>(emb4, t, pts, ws, N);
        k_final<<<1, 256, 0, stream>>>(ws, out);
    } else {
        k_init_fb<<<1, 256, 0, stream>>>(ws);
        k_sums_fb<<<FB_GRID, FB_BLK, 0, stream>>>(emb4, t, ws, N);
        k_intra_fb<<<FB_GRID, 256, 0, stream>>>(emb4, t, pts, ws, N);
        k_final_fb<<<1, 256, 0, stream>>>(ws, out);
    }
}